// Round 3
// baseline (970.383 us; speedup 1.0000x reference)
//
#include <hip/hip_runtime.h>
#include <cstdint>
#include <cstddef>

typedef __bf16 bf16;
typedef float f32x4 __attribute__((ext_vector_type(4)));
typedef bf16  bf16x4 __attribute__((ext_vector_type(4)));
typedef bf16  bf16x8 __attribute__((ext_vector_type(8)));

#define DIMD   2048
#define HEADS  32
#define DH     64
#define FFI    8192
#define FUSEDN 18560
#define FUSEDP 18688   // padded to 73*256
#define BB     2
#define NN     2048
#define MROWS  4096   // BB*NN
#define K2     10240  // DIMD + FFI

#define VMW(n) asm volatile("s_waitcnt vmcnt(" #n ")" ::: "memory")

// async global->LDS, 16B per lane, wave-uniform LDS base
__device__ __forceinline__ void gl_lds16(const void* g, void* l) {
  __builtin_amdgcn_global_load_lds(
      (__attribute__((address_space(1))) void*)const_cast<void*>(g),
      (__attribute__((address_space(3))) void*)l, 16, 0, 0);
}

struct SrcT { const bf16* g; long ldk; };

// Stage one 512-chunk (8KB) instruction of a [rows][64] bf16 K-tile into LDS.
// LDS dest is linear (global_load_lds constraint); T2 swizzle applied on the
// GLOBAL source: LDS chunk (row, c) receives global chunk (row, c^(row&7)).
__device__ __forceinline__ void stage_instr(const bf16* g, long ldk,
                                            bf16* region, int instr, int tid) {
  int row = instr * 64 + (tid >> 3);
  int cs = (tid & 7) ^ (row & 7);
  gl_lds16(g + (size_t)row * ldk + cs * 8,
           region + (size_t)(instr * 512 + (tid & ~63)) * 8);
}

// ---- 8-phase double-buffered GEMM core (BM = MFR*32, BN = 256, BK = 64) ----
// Phases p1-4 compute buf0 (tile t0), p5-8 buf1 (tile t1). Staging: 2 gl_lds
// per phase (even interleave); counted vmcnt waits only at p4/p8.
template <int MFR, typename FA, typename FB>
__device__ __forceinline__ void gemm_core(FA fa, FB fb, const int NT,
    bf16* AsB, bf16* BsB, f32x4 (&acc)[MFR][4],
    const int tid, const int wrow, const int nbase, const int l15, const int h4)
{
  constexpr int ASZ = MFR * 32 * 64;
  constexpr int BSZ = 256 * 64;
  constexpr int AIN = MFR / 2;   // gl_lds instructions per A tile
  bf16x8 af[MFR], b0, b1;

  // hoisted per-lane LDS read base pointers: [buf][ks], all else is imm offset
  const char* aP[2][2]; const char* bP[2][2];
  {
    const int arow = wrow + l15, brow = nbase + l15;
#pragma unroll
    for (int bb = 0; bb < 2; bb++)
#pragma unroll
      for (int ks = 0; ks < 2; ks++) {
        aP[bb][ks] = (const char*)(AsB + bb * ASZ) + arow * 128 + (((ks * 4 + h4) ^ (arow & 7)) * 16);
        bP[bb][ks] = (const char*)(BsB + bb * BSZ) + brow * 128 + (((ks * 4 + h4) ^ (brow & 7)) * 16);
      }
  }

#define SA(t, q) do { SrcT s_ = fa(t); stage_instr(s_.g, s_.ldk, AsB + ((t)&1)*ASZ, (q), tid); } while(0)
#define SB(t, q) do { SrcT s_ = fb(t); stage_instr(s_.g, s_.ldk, BsB + ((t)&1)*BSZ, (q), tid); } while(0)

  // prologue: tile0 (A+B) and tile1's A; drain all but tile1's A loads
#pragma unroll
  for (int q = 0; q < AIN; q++) SA(0, q);
#pragma unroll
  for (int q = 0; q < 4; q++) SB(0, q);
#pragma unroll
  for (int q = 0; q < AIN; q++) SA(1, q);
  asm volatile("s_waitcnt vmcnt(%0)" :: "i"(AIN) : "memory");
  __builtin_amdgcn_s_barrier();

#define PH(bb, ks, nh, STG, WCODE) do {                                       \
    if ((nh) == 0) {                                                          \
      _Pragma("unroll")                                                       \
      for (int m_ = 0; m_ < MFR; m_++)                                        \
        af[m_] = *(const bf16x8*)(aP[bb][ks] + m_ * 2048);                    \
    }                                                                         \
    b0 = *(const bf16x8*)(bP[bb][ks] + (nh) * 4096);                          \
    b1 = *(const bf16x8*)(bP[bb][ks] + (nh) * 4096 + 2048);                   \
    STG                                                                       \
    __builtin_amdgcn_s_barrier();                                             \
    asm volatile("s_waitcnt lgkmcnt(0)" ::: "memory");                        \
    __builtin_amdgcn_sched_barrier(0);                                        \
    __builtin_amdgcn_s_setprio(1);                                            \
    _Pragma("unroll")                                                         \
    for (int m_ = 0; m_ < MFR; m_++) {                                        \
      acc[m_][(nh)*2+0] = __builtin_amdgcn_mfma_f32_16x16x32_bf16(af[m_], b0, acc[m_][(nh)*2+0], 0,0,0); \
      acc[m_][(nh)*2+1] = __builtin_amdgcn_mfma_f32_16x16x32_bf16(af[m_], b1, acc[m_][(nh)*2+1], 0,0,0); \
    }                                                                         \
    __builtin_amdgcn_s_setprio(0);                                            \
    WCODE                                                                     \
    __builtin_amdgcn_s_barrier();                                             \
  } while (0)

  for (int it = 0; it < NT / 2; ++it) {
    const int t0 = 2 * it, t1 = t0 + 1;
    const bool gg = (t0 + 2) < NT;   // false only on the last iteration
    PH(0, 0, 0, SB(t1, 0); SB(t1, 1); , );
    PH(0, 0, 1, SB(t1, 2); SB(t1, 3); , );
    PH(0, 1, 0, , );
    PH(0, 1, 1,
       if (gg) { SA(t0 + 2, 0); SA(t0 + 2, 1); } ,
       if (gg) { VMW(2); } else { VMW(0); } );
    PH(1, 0, 0,
       if (gg) { if constexpr (AIN > 2) { SA(t0 + 2, 2); SA(t0 + 2, 3); }
                 SB(t0 + 2, 0); SB(t0 + 2, 1); } , );
    PH(1, 0, 1, if (gg) { SB(t0 + 2, 2); SB(t0 + 2, 3); } , );
    PH(1, 1, 0, , );
    PH(1, 1, 1,
       if (gg) { _Pragma("unroll") for (int q_ = 0; q_ < AIN; q_++) SA(t1 + 2, q_); } ,
       if (gg) { asm volatile("s_waitcnt vmcnt(%0)" :: "i"(AIN) : "memory"); }
       else    { VMW(0); } );
  }
#undef PH
#undef SA
#undef SB
}

// ---------------- fp32 -> bf16 flat conversion ----------------
__global__ void k_cvt_flat(const float* __restrict__ s, bf16* __restrict__ d, long total8) {
  long stride = (long)gridDim.x * blockDim.x;
  for (long i = (long)blockIdx.x * blockDim.x + threadIdx.x; i < total8; i += stride) {
    long e = i << 3;
    float4 v0 = *(const float4*)(s + e);
    float4 v1 = *(const float4*)(s + e + 4);
    bf16x8 o;
    o[0]=(bf16)v0.x; o[1]=(bf16)v0.y; o[2]=(bf16)v0.z; o[3]=(bf16)v0.w;
    o[4]=(bf16)v1.x; o[5]=(bf16)v1.y; o[6]=(bf16)v1.z; o[7]=(bf16)v1.w;
    *(bf16x8*)(d + e) = o;
  }
}

// ---------------- fp32 -> bf16 strided conversion (pow2 cols) ----------------
__global__ void k_cvt_str8(const float* __restrict__ s, bf16* __restrict__ d,
                           long total8, int colshift, int dstride, int doff) {
  long stride = (long)gridDim.x * blockDim.x;
  for (long i = (long)blockIdx.x * blockDim.x + threadIdx.x; i < total8; i += stride) {
    long e = i << 3;
    long r = e >> colshift;
    int  c = (int)(e & ((1L << colshift) - 1));
    float4 v0 = *(const float4*)(s + e);
    float4 v1 = *(const float4*)(s + e + 4);
    bf16x8 o;
    o[0]=(bf16)v0.x; o[1]=(bf16)v0.y; o[2]=(bf16)v0.z; o[3]=(bf16)v0.w;
    o[4]=(bf16)v1.x; o[5]=(bf16)v1.y; o[6]=(bf16)v1.z; o[7]=(bf16)v1.w;
    *(bf16x8*)(d + r * (long)dstride + doff + c) = o;
  }
}

// ---------------- LayerNorm (per row) -> bf16 ----------------
__global__ __launch_bounds__(256) void k_ln(const float* __restrict__ x,
                                            const float* __restrict__ g,
                                            bf16* __restrict__ xn) {
  int row = blockIdx.x, t = threadIdx.x;
  const float4* xr = (const float4*)(x + (size_t)row * DIMD);
  float4 a = xr[t*2], b = xr[t*2+1];
  float s  = a.x+a.y+a.z+a.w + b.x+b.y+b.z+b.w;
  float s2 = a.x*a.x+a.y*a.y+a.z*a.z+a.w*a.w + b.x*b.x+b.y*b.y+b.z*b.z+b.w*b.w;
  for (int o = 1; o < 64; o <<= 1) { s += __shfl_xor(s, o); s2 += __shfl_xor(s2, o); }
  __shared__ float rs[8];
  if ((t & 63) == 0) { rs[t>>6] = s; rs[4 + (t>>6)] = s2; }
  __syncthreads();
  s = rs[0]+rs[1]+rs[2]+rs[3]; s2 = rs[4]+rs[5]+rs[6]+rs[7];
  float mu = s * (1.f/DIMD);
  float var = s2 * (1.f/DIMD) - mu*mu;
  float rstd = rsqrtf(var + 1e-5f);
  const float4* gr = (const float4*)g;
  float4 g0 = gr[t*2], g1 = gr[t*2+1];
  bf16x8 o;
  o[0]=(bf16)((a.x-mu)*rstd*g0.x); o[1]=(bf16)((a.y-mu)*rstd*g0.y);
  o[2]=(bf16)((a.z-mu)*rstd*g0.z); o[3]=(bf16)((a.w-mu)*rstd*g0.w);
  o[4]=(bf16)((b.x-mu)*rstd*g1.x); o[5]=(bf16)((b.y-mu)*rstd*g1.y);
  o[6]=(bf16)((b.z-mu)*rstd*g1.z); o[7]=(bf16)((b.w-mu)*rstd*g1.w);
  *(bf16x8*)(xn + (size_t)row * DIMD + t*8) = o;
}

// ---------------- GEMM1: proj = xn(4096x2048) @ Wf^T, routed epilogue ----------------
__global__ __launch_bounds__(512, 2) void k_gemm1(const bf16* __restrict__ xn,
                                                  const bf16* __restrict__ wf,
                                                  bf16* __restrict__ q_raw,
                                                  bf16* __restrict__ k_buf,
                                                  bf16* __restrict__ v_t,
                                                  bf16* __restrict__ proj_ff) {
  __shared__ bf16 As[2*256*64];
  __shared__ bf16 Bs[2*256*64];
  const int tid = threadIdx.x, w = tid >> 6, l = tid & 63;
  const int l15 = l & 15, h4 = l >> 4;
  const int wr = w >> 2, wc = w & 3;
  const int nwg = gridDim.x, bid = blockIdx.x;
  const int bs = (bid & 7) * (nwg >> 3) + (bid >> 3);   // XCD swizzle (1168 % 8 == 0)
  const int mt = bs & 15, nt = bs >> 4;
  const int m0 = mt * 256, f0 = nt * 256;
  const int wrow = wr * 128, nbase = wc * 64;

  f32x4 acc[8][4];
#pragma unroll
  for (int i = 0; i < 8; i++)
#pragma unroll
    for (int j = 0; j < 4; j++) acc[i][j] = (f32x4){0.f,0.f,0.f,0.f};

  auto fa = [&](int t) -> SrcT { return SrcT{ xn + (size_t)m0 * DIMD + t * 64, (long)DIMD }; };
  auto fb = [&](int t) -> SrcT { return SrcT{ wf + (size_t)f0 * DIMD + t * 64, (long)DIMD }; };
  gemm_core<8>(fa, fb, DIMD / 64, As, Bs, acc, tid, wrow, nbase, l15, h4);

#pragma unroll
  for (int m_ = 0; m_ < 8; m_++)
#pragma unroll
    for (int nf = 0; nf < 4; nf++) {
      int fcol = f0 + nbase + nf*16 + l15;
      if (fcol < FUSEDN) {
#pragma unroll
        for (int j = 0; j < 4; j++) {
          int m = m0 + wrow + m_*16 + h4*4 + j;
          bf16 bv = (bf16)acc[m_][nf][j];
          int b = m >> 11, n = m & 2047;
          if (fcol < 2048) {
            int hh = fcol >> 6, d = fcol & 63;
            q_raw[(((size_t)(b*HEADS + hh) * NN + n) << 6) + d] = bv;
          } else if (fcol < 2112) {
            k_buf[(((size_t)(b*NN + n)) << 6) + (fcol - 2048)] = bv;
          } else if (fcol < 2176) {
            v_t[(((size_t)(b*DH + (fcol - 2112))) << 11) + n] = bv;
          } else {
            proj_ff[((size_t)m << 14) + (fcol - 2176)] = bv;
          }
        }
      }
    }
}

// ---------------- GEMM2: out = [O | ffh](4096x10240) @ Wcat^T -> fp32 ----------------
__global__ __launch_bounds__(512, 2) void k_gemm2(const bf16* __restrict__ u_o,
                                                  const bf16* __restrict__ ffh,
                                                  const bf16* __restrict__ wcat,
                                                  float* __restrict__ out) {
  __shared__ bf16 As[2*128*64];
  __shared__ bf16 Bs[2*256*64];
  const int tid = threadIdx.x, w = tid >> 6, l = tid & 63;
  const int l15 = l & 15, h4 = l >> 4;
  const int wr = w >> 2, wc = w & 3;
  const int bid = blockIdx.x;
  const int bs = (bid & 7) * 32 + (bid >> 3);           // XCD swizzle (256 blocks)
  const int mt = bs & 31, nt = bs >> 5;
  const int m0 = mt * 128, f0 = nt * 256;
  const int wrow = wr * 64, nbase = wc * 64;

  f32x4 acc[4][4];
#pragma unroll
  for (int i = 0; i < 4; i++)
#pragma unroll
    for (int j = 0; j < 4; j++) acc[i][j] = (f32x4){0.f,0.f,0.f,0.f};

  auto fa = [&](int t) -> SrcT {
    int k0 = t * 64;
    if (k0 < DIMD) return SrcT{ u_o + (size_t)m0 * DIMD + k0, (long)DIMD };
    return SrcT{ ffh + (size_t)m0 * 16384 + (k0 - DIMD), (long)16384 };
  };
  auto fb = [&](int t) -> SrcT { return SrcT{ wcat + (size_t)f0 * K2 + t * 64, (long)K2 }; };
  gemm_core<4>(fa, fb, K2 / 64, As, Bs, acc, tid, wrow, nbase, l15, h4);

#pragma unroll
  for (int m_ = 0; m_ < 4; m_++)
#pragma unroll
    for (int nf = 0; nf < 4; nf++) {
      int fcol = f0 + nbase + nf*16 + l15;
#pragma unroll
      for (int j = 0; j < 4; j++) {
        int m = m0 + wrow + m_*16 + h4*4 + j;
        out[(size_t)m * DIMD + fcol] = acc[m_][nf][j];
      }
    }
}

// ---------------- RoPE in-place on q_raw (with 1/8 fold) and k_buf (inverse scale) ----------------
__global__ void k_rope(bf16* __restrict__ q_raw, bf16* __restrict__ k_buf) {
  const long QT = (long)BB*HEADS*NN*32;
  const long TOT = QT + (long)BB*NN*32;
  long gid = (long)blockIdx.x * blockDim.x + threadIdx.x;
  if (gid >= TOT) return;
  bool isq = gid < QT;
  long idx = isq ? gid : gid - QT;
  int  i = (int)(idx & 31);
  long row = idx >> 5;
  int  n = (int)(row & (NN - 1));
  bf16* base = (isq ? q_raw : k_buf) + row * DH;
  float t1 = (float)base[i];
  float t2 = (float)base[i + 32];
  float inv_freq = exp2f((float)i * -0.4152410118f);   // 10000^(-i/32)
  float th = (float)n * inv_freq;
  float sn, cs;
  __sincosf(th, &sn, &cs);
  float power = ((float)n - (float)(NN/2)) * (1.f/512.f);
  float sb = ((float)(2*i) + 25.6f) * (1.f/89.6f);
  float sc = exp2f((isq ? power : -power) * __log2f(sb));
  float mm = isq ? 0.125f : 1.0f;
  float o1 = (t1*cs - t2*sn) * sc * mm;
  float o2 = (t2*cs + t1*sn) * sc * mm;
  base[i]      = (bf16)o1;
  base[i + 32] = (bf16)o2;
}

// ---------------- causal MQA flash attention ----------------
__global__ __launch_bounds__(256) void k_attn(const bf16* __restrict__ qbuf,
                                              const bf16* __restrict__ kbuf,
                                              const bf16* __restrict__ vtb,
                                              bf16* __restrict__ uo) {
  __shared__ bf16 Qs[128*64];
  __shared__ bf16 Ks[32*64];
  __shared__ bf16 Vs[64*32];
  const int tid = threadIdx.x, w = tid >> 6, l = tid & 63;
  const int l15 = l & 15, h4 = l >> 4;
  const int bid = blockIdx.x;
  const int qt = bid & 15, bh = bid >> 4;
  const int h = bh & (HEADS - 1), b = bh >> 5;
  const int q0 = qt * 128;
  const bf16* Qg = qbuf + ((size_t)(b*HEADS + h) * NN + q0) * DH;
  const bf16* Kg = kbuf + (size_t)b * NN * DH;
  const bf16* Vg = vtb + (size_t)b * DH * NN;

#pragma unroll
  for (int c = 0; c < 4; c++) {
    int chunk = c*256 + tid;
    int r = chunk >> 3, cc = chunk & 7;
    int col8 = (cc ^ (r & 7)) << 3;
    gl_lds16(Qg + (size_t)r*DH + col8, Qs + ((size_t)(chunk & ~63) << 3));
  }
  __syncthreads();

  const int wq0 = q0 + w*32;
  bf16x8 qfr[2][2];
#pragma unroll
  for (int qf = 0; qf < 2; qf++)
#pragma unroll
    for (int c = 0; c < 2; c++) {
      int row = w*32 + qf*16 + l15;
      int x = (64*c + 16*h4) ^ (16*(row & 7));
      qfr[qf][c] = *(const bf16x8*)((const char*)Qs + row*128 + x);
    }

  f32x4 zf = {0.f,0.f,0.f,0.f};
  f32x4 o_[2][4];
#pragma unroll
  for (int qf = 0; qf < 2; qf++)
#pragma unroll
    for (int nf = 0; nf < 4; nf++) o_[qf][nf] = zf;
  float mrun[2] = {-3e38f, -3e38f};
  float lrun[2] = {0.f, 0.f};

  const int nsteps = (q0 + 128) >> 5;
  for (int kt = 0; kt < nsteps; kt++) {
    const int kv0 = kt << 5;
    {
      int r = tid >> 3, cc = tid & 7;
      int col8 = (cc ^ (r & 7)) << 3;
      gl_lds16(Kg + (size_t)(kv0 + r)*DH + col8, Ks + ((size_t)(tid & ~63) << 3));
    }
    {
      int d = tid >> 2, cc = tid & 3;
      int col8 = (cc ^ (d & 3)) << 3;
      gl_lds16(Vg + (size_t)d*NN + kv0 + col8, Vs + ((size_t)(tid & ~63) << 3));
    }
    __syncthreads();
    if (kv0 <= wq0 + 31) {
      bf16x8 ka[2][2];
#pragma unroll
      for (int kvf = 0; kvf < 2; kvf++)
#pragma unroll
        for (int c = 0; c < 2; c++) {
          int r = kvf*16 + l15;
          int x = (64*c + 16*h4) ^ (16*(r & 7));
          ka[kvf][c] = *(const bf16x8*)((const char*)Ks + r*128 + x);
        }
      f32x4 st[2][2];
#pragma unroll
      for (int kvf = 0; kvf < 2; kvf++)
#pragma unroll
        for (int qf = 0; qf < 2; qf++) {
          f32x4 s = __builtin_amdgcn_mfma_f32_16x16x32_bf16(ka[kvf][0], qfr[qf][0], zf, 0, 0, 0);
          s = __builtin_amdgcn_mfma_f32_16x16x32_bf16(ka[kvf][1], qfr[qf][1], s, 0, 0, 0);
          st[kvf][qf] = s;
        }
      if (kv0 + 31 > wq0) {
#pragma unroll
        for (int kvf = 0; kvf < 2; kvf++)
#pragma unroll
          for (int j = 0; j < 4; j++) {
            int kvg = kv0 + kvf*16 + h4*4 + j;
#pragma unroll
            for (int qf = 0; qf < 2; qf++) {
              int qg = wq0 + qf*16 + l15;
              if (kvg > qg) st[kvf][qf][j] = -3e38f;
            }
          }
      }
      bf16x8 pa[2];
#pragma unroll
      for (int qf = 0; qf < 2; qf++) {
        float vmax = -3e38f;
#pragma unroll
        for (int kvf = 0; kvf < 2; kvf++)
#pragma unroll
          for (int j = 0; j < 4; j++) vmax = fmaxf(vmax, st[kvf][qf][j]);
        vmax = fmaxf(vmax, __shfl_xor(vmax, 16));
        vmax = fmaxf(vmax, __shfl_xor(vmax, 32));
        float mnew = fmaxf(mrun[qf], vmax);
        float corr = __expf(mrun[qf] - mnew);
        float ps = 0.f;
        float pv_[8];
#pragma unroll
        for (int kvf = 0; kvf < 2; kvf++)
#pragma unroll
          for (int j = 0; j < 4; j++) {
            float p = __expf(st[kvf][qf][j] - mnew);
            pv_[kvf*4 + j] = p; ps += p;
          }
        ps += __shfl_xor(ps, 16);
        ps += __shfl_xor(ps, 32);
        lrun[qf] = lrun[qf]*corr + ps;
        mrun[qf] = mnew;
        bf16x8 t;
#pragma unroll
        for (int i = 0; i < 8; i++) t[i] = (bf16)pv_[i];
        pa[qf] = t;
#pragma unroll
        for (int j = 0; j < 4; j++) {
          float cj = __shfl(corr, (l & 48) | (h4*4 + j), 64);
#pragma unroll
          for (int nf = 0; nf < 4; nf++) o_[qf][nf][j] *= cj;
        }
      }
#pragma unroll
      for (int nf = 0; nf < 4; nf++) {
        int d_ = nf*16 + l15;
        int swz = 16*(d_ & 3);
        const char* vrow = (const char*)Vs + d_*64;
        bf16x4 v0 = *(const bf16x4*)(vrow + ((8*h4) ^ swz));
        bf16x4 v1 = *(const bf16x4*)(vrow + ((8*h4 + 32) ^ swz));
        bf16x8 vb = __builtin_shufflevector(v0, v1, 0,1,2,3,4,5,6,7);
#pragma unroll
        for (int qf = 0; qf < 2; qf++)
          o_[qf][nf] = __builtin_amdgcn_mfma_f32_16x16x32_bf16(pa[qf], vb, o_[qf][nf], 0, 0, 0);
      }
    }
    __syncthreads();
  }
#pragma unroll
  for (int qf = 0; qf < 2; qf++) {
    float inv = 1.f / lrun[qf];
#pragma unroll
    for (int j = 0; j < 4; j++) {
      float ij = __shfl(inv, (l & 48) | (h4*4 + j), 64);
      int qg = wq0 + qf*16 + h4*4 + j;
      size_t rowoff = (size_t)(b*NN + qg) * DIMD + h*DH;
#pragma unroll
      for (int nf = 0; nf < 4; nf++)
        uo[rowoff + nf*16 + l15] = (bf16)(o_[qf][nf][j] * ij);
    }
  }
}

// ---------------- SiLU gating, in-place over ff_x half of proj_ff ----------------
__global__ void k_silu(bf16* __restrict__ pf) {
  const long total4 = (long)MROWS * FFI / 4;
  long stride = (long)gridDim.x * blockDim.x;
  for (long i = (long)blockIdx.x * blockDim.x + threadIdx.x; i < total4; i += stride) {
    long e = i << 2;
    long m = e >> 13;
    int  c = (int)(e & (FFI - 1));
    bf16* px = pf + (m << 14) + c;
    bf16x4 fx = *(const bf16x4*)px;
    bf16x4 gt = *(const bf16x4*)(px + FFI);
    bf16x4 r;
#pragma unroll
    for (int k = 0; k < 4; k++) {
      float g = (float)gt[k], f = (float)fx[k];
      float s = g * (1.f / (1.f + __expf(-g)));
      r[k] = (bf16)(s * f);
    }
    *(bf16x4*)px = r;
  }
}

extern "C" void kernel_launch(void* const* d_in, const int* in_sizes, int n_in,
                              void* d_out, int out_size, void* d_ws, size_t ws_size,
                              hipStream_t stream) {
  const float* x     = (const float*)d_in[0];
  const float* gamma = (const float*)d_in[1];
  const float* Wf    = (const float*)d_in[2];
  const float* Wao   = (const float*)d_in[3];
  const float* Wff   = (const float*)d_in[4];
  float* out = (float*)d_out;
  char* ws = (char*)d_ws;

  size_t o = 0;
  bf16* wfb     = (bf16*)(ws + o); o += (size_t)FUSEDP * DIMD * 2;   // padded
  bf16* wcat    = wfb;                                               // aliased after GEMM1
  bf16* xn      = (bf16*)(ws + o); o += (size_t)MROWS * DIMD * 2;
  bf16* q_raw   = (bf16*)(ws + o); o += (size_t)BB*HEADS*NN*DH * 2;
  bf16* k_buf   = (bf16*)(ws + o); o += (size_t)BB*NN*DH * 2;
  bf16* v_t     = (bf16*)(ws + o); o += (size_t)BB*DH*NN * 2;
  bf16* proj_ff = (bf16*)(ws + o); o += (size_t)MROWS * 2*FFI * 2;
  bf16* u_o     = (bf16*)(ws + o); o += (size_t)MROWS * DIMD * 2;

  k_cvt_flat<<<2048, 256, 0, stream>>>(Wf, wfb, (long)FUSEDN*DIMD/8);
  k_ln<<<MROWS, 256, 0, stream>>>(x, gamma, xn);
  k_gemm1<<<(FUSEDP/256)*(MROWS/256), 512, 0, stream>>>(xn, wfb, q_raw, k_buf, v_t, proj_ff);
  k_cvt_str8<<<512,  256, 0, stream>>>(Wao, wcat, (long)DIMD*DIMD/8, 11, K2, 0);
  k_cvt_str8<<<1024, 256, 0, stream>>>(Wff, wcat, (long)DIMD*FFI/8,  13, K2, DIMD);
  {
    long tot = (long)BB*HEADS*NN*32 + (long)BB*NN*32;
    k_rope<<<(int)((tot + 255) / 256), 256, 0, stream>>>(q_raw, k_buf);
  }
  k_attn<<<BB*HEADS*(NN/128), 256, 0, stream>>>(q_raw, k_buf, v_t, u_o);
  k_silu<<<2048, 256, 0, stream>>>(proj_ff);
  k_gemm2<<<(MROWS/128)*(DIMD/256), 512, 0, stream>>>(u_o, proj_ff, wcat, out);
}

// Round 4
// 968.405 us; speedup vs baseline: 1.0020x; 1.0020x over previous
//
#include <hip/hip_runtime.h>
#include <cstdint>
#include <cstddef>

typedef __bf16 bf16;
typedef float f32x4 __attribute__((ext_vector_type(4)));
typedef bf16  bf16x4 __attribute__((ext_vector_type(4)));
typedef bf16  bf16x8 __attribute__((ext_vector_type(8)));

#define DIMD   2048
#define HEADS  32
#define DH     64
#define FFI    8192
#define FUSEDN 18560
#define FUSEDP 18688   // padded to 73*256
#define BB     2
#define NN     2048
#define MROWS  4096   // BB*NN
#define K2     10240  // DIMD + FFI

#define VMW(n) asm volatile("s_waitcnt vmcnt(" #n ")" ::: "memory")

// async global->LDS, 16B per lane, wave-uniform LDS base
__device__ __forceinline__ void gl_lds16(const void* g, void* l) {
  __builtin_amdgcn_global_load_lds(
      (__attribute__((address_space(1))) void*)const_cast<void*>(g),
      (__attribute__((address_space(3))) void*)l, 16, 0, 0);
}

struct SrcT { const bf16* g; long ldk; };

// Stage one 512-chunk (8KB) instruction of a [rows][64] bf16 K-tile into LDS.
// LDS dest is linear (global_load_lds constraint); T2 swizzle applied on the
// GLOBAL source: LDS chunk (row, c) receives global chunk (row, c^(row&7)).
__device__ __forceinline__ void stage_instr(const bf16* g, long ldk,
                                            bf16* region, int instr, int tid) {
  int row = instr * 64 + (tid >> 3);
  int cs = (tid & 7) ^ (row & 7);
  gl_lds16(g + (size_t)row * ldk + cs * 8,
           region + (size_t)(instr * 512 + (tid & ~63)) * 8);
}

// ---- 8-phase double-buffered GEMM core (BM = MFR*32, BN = 256, BK = 64) ----
// Phases p1-4 compute buf0 (tile t0), p5-8 buf1 (tile t1). Staging: 2 gl_lds
// per phase (even interleave); counted vmcnt waits only at p4/p8.
// R4 change: NO per-phase lgkmcnt(0)/sched_barrier(0) — compiler emits
// fine-grained lgkm waits for the C++ ds_reads (m97/m141 evidence).
template <int MFR, typename FA, typename FB>
__device__ __forceinline__ void gemm_core(FA fa, FB fb, const int NT,
    bf16* AsB, bf16* BsB, f32x4 (&acc)[MFR][4],
    const int tid, const int wrow, const int nbase, const int l15, const int h4)
{
  constexpr int ASZ = MFR * 32 * 64;
  constexpr int BSZ = 256 * 64;
  constexpr int AIN = MFR / 2;   // gl_lds instructions per A tile
  bf16x8 af[MFR], b0, b1;

  // hoisted per-lane LDS read base pointers: [buf][ks], all else is imm offset
  const char* aP[2][2]; const char* bP[2][2];
  {
    const int arow = wrow + l15, brow = nbase + l15;
#pragma unroll
    for (int bb = 0; bb < 2; bb++)
#pragma unroll
      for (int ks = 0; ks < 2; ks++) {
        aP[bb][ks] = (const char*)(AsB + bb * ASZ) + arow * 128 + (((ks * 4 + h4) ^ (arow & 7)) * 16);
        bP[bb][ks] = (const char*)(BsB + bb * BSZ) + brow * 128 + (((ks * 4 + h4) ^ (brow & 7)) * 16);
      }
  }

#define SA(t, q) do { SrcT s_ = fa(t); stage_instr(s_.g, s_.ldk, AsB + ((t)&1)*ASZ, (q), tid); } while(0)
#define SB(t, q) do { SrcT s_ = fb(t); stage_instr(s_.g, s_.ldk, BsB + ((t)&1)*BSZ, (q), tid); } while(0)

  // prologue: tile0 (A+B) and tile1's A; drain all but tile1's A loads
#pragma unroll
  for (int q = 0; q < AIN; q++) SA(0, q);
#pragma unroll
  for (int q = 0; q < 4; q++) SB(0, q);
#pragma unroll
  for (int q = 0; q < AIN; q++) SA(1, q);
  asm volatile("s_waitcnt vmcnt(%0)" :: "i"(AIN) : "memory");
  __builtin_amdgcn_s_barrier();

#define PH(bb, ks, nh, STG, WCODE) do {                                       \
    if ((nh) == 0) {                                                          \
      _Pragma("unroll")                                                       \
      for (int m_ = 0; m_ < MFR; m_++)                                        \
        af[m_] = *(const bf16x8*)(aP[bb][ks] + m_ * 2048);                    \
    }                                                                         \
    b0 = *(const bf16x8*)(bP[bb][ks] + (nh) * 4096);                          \
    b1 = *(const bf16x8*)(bP[bb][ks] + (nh) * 4096 + 2048);                   \
    STG                                                                       \
    __builtin_amdgcn_s_barrier();                                             \
    __builtin_amdgcn_s_setprio(1);                                            \
    _Pragma("unroll")                                                         \
    for (int m_ = 0; m_ < MFR; m_++) {                                        \
      acc[m_][(nh)*2+0] = __builtin_amdgcn_mfma_f32_16x16x32_bf16(af[m_], b0, acc[m_][(nh)*2+0], 0,0,0); \
      acc[m_][(nh)*2+1] = __builtin_amdgcn_mfma_f32_16x16x32_bf16(af[m_], b1, acc[m_][(nh)*2+1], 0,0,0); \
    }                                                                         \
    __builtin_amdgcn_s_setprio(0);                                            \
    WCODE                                                                     \
    __builtin_amdgcn_s_barrier();                                             \
  } while (0)

  for (int it = 0; it < NT / 2; ++it) {
    const int t0 = 2 * it, t1 = t0 + 1;
    const bool gg = (t0 + 2) < NT;   // false only on the last iteration
    PH(0, 0, 0, SB(t1, 0); SB(t1, 1); , );
    PH(0, 0, 1, SB(t1, 2); SB(t1, 3); , );
    PH(0, 1, 0, , );
    PH(0, 1, 1,
       if (gg) { SA(t0 + 2, 0); SA(t0 + 2, 1); } ,
       if (gg) { VMW(2); } else { VMW(0); } );
    PH(1, 0, 0,
       if (gg) { if constexpr (AIN > 2) { SA(t0 + 2, 2); SA(t0 + 2, 3); }
                 SB(t0 + 2, 0); SB(t0 + 2, 1); } , );
    PH(1, 0, 1, if (gg) { SB(t0 + 2, 2); SB(t0 + 2, 3); } , );
    PH(1, 1, 0, , );
    PH(1, 1, 1,
       if (gg) { _Pragma("unroll") for (int q_ = 0; q_ < AIN; q_++) SA(t1 + 2, q_); } ,
       if (gg) { asm volatile("s_waitcnt vmcnt(%0)" :: "i"(AIN) : "memory"); }
       else    { VMW(0); } );
  }
#undef PH
#undef SA
#undef SB
}

// ---------------- fp32 -> bf16 flat conversion ----------------
__global__ void k_cvt_flat(const float* __restrict__ s, bf16* __restrict__ d, long total8) {
  long stride = (long)gridDim.x * blockDim.x;
  for (long i = (long)blockIdx.x * blockDim.x + threadIdx.x; i < total8; i += stride) {
    long e = i << 3;
    float4 v0 = *(const float4*)(s + e);
    float4 v1 = *(const float4*)(s + e + 4);
    bf16x8 o;
    o[0]=(bf16)v0.x; o[1]=(bf16)v0.y; o[2]=(bf16)v0.z; o[3]=(bf16)v0.w;
    o[4]=(bf16)v1.x; o[5]=(bf16)v1.y; o[6]=(bf16)v1.z; o[7]=(bf16)v1.w;
    *(bf16x8*)(d + e) = o;
  }
}

// ---------------- fp32 -> bf16 strided conversion (pow2 cols) ----------------
__global__ void k_cvt_str8(const float* __restrict__ s, bf16* __restrict__ d,
                           long total8, int colshift, int dstride, int doff) {
  long stride = (long)gridDim.x * blockDim.x;
  for (long i = (long)blockIdx.x * blockDim.x + threadIdx.x; i < total8; i += stride) {
    long e = i << 3;
    long r = e >> colshift;
    int  c = (int)(e & ((1L << colshift) - 1));
    float4 v0 = *(const float4*)(s + e);
    float4 v1 = *(const float4*)(s + e + 4);
    bf16x8 o;
    o[0]=(bf16)v0.x; o[1]=(bf16)v0.y; o[2]=(bf16)v0.z; o[3]=(bf16)v0.w;
    o[4]=(bf16)v1.x; o[5]=(bf16)v1.y; o[6]=(bf16)v1.z; o[7]=(bf16)v1.w;
    *(bf16x8*)(d + r * (long)dstride + doff + c) = o;
  }
}

// ---------------- LayerNorm (per row) -> bf16 ----------------
__global__ __launch_bounds__(256) void k_ln(const float* __restrict__ x,
                                            const float* __restrict__ g,
                                            bf16* __restrict__ xn) {
  int row = blockIdx.x, t = threadIdx.x;
  const float4* xr = (const float4*)(x + (size_t)row * DIMD);
  float4 a = xr[t*2], b = xr[t*2+1];
  float s  = a.x+a.y+a.z+a.w + b.x+b.y+b.z+b.w;
  float s2 = a.x*a.x+a.y*a.y+a.z*a.z+a.w*a.w + b.x*b.x+b.y*b.y+b.z*b.z+b.w*b.w;
  for (int o = 1; o < 64; o <<= 1) { s += __shfl_xor(s, o); s2 += __shfl_xor(s2, o); }
  __shared__ float rs[8];
  if ((t & 63) == 0) { rs[t>>6] = s; rs[4 + (t>>6)] = s2; }
  __syncthreads();
  s = rs[0]+rs[1]+rs[2]+rs[3]; s2 = rs[4]+rs[5]+rs[6]+rs[7];
  float mu = s * (1.f/DIMD);
  float var = s2 * (1.f/DIMD) - mu*mu;
  float rstd = rsqrtf(var + 1e-5f);
  const float4* gr = (const float4*)g;
  float4 g0 = gr[t*2], g1 = gr[t*2+1];
  bf16x8 o;
  o[0]=(bf16)((a.x-mu)*rstd*g0.x); o[1]=(bf16)((a.y-mu)*rstd*g0.y);
  o[2]=(bf16)((a.z-mu)*rstd*g0.z); o[3]=(bf16)((a.w-mu)*rstd*g0.w);
  o[4]=(bf16)((b.x-mu)*rstd*g1.x); o[5]=(bf16)((b.y-mu)*rstd*g1.y);
  o[6]=(bf16)((b.z-mu)*rstd*g1.z); o[7]=(bf16)((b.w-mu)*rstd*g1.w);
  *(bf16x8*)(xn + (size_t)row * DIMD + t*8) = o;
}

// ---------------- GEMM1: proj = xn(4096x2048) @ Wf^T, routed epilogue ----------------
__global__ __launch_bounds__(512, 2) void k_gemm1(const bf16* __restrict__ xn,
                                                  const bf16* __restrict__ wf,
                                                  bf16* __restrict__ q_raw,
                                                  bf16* __restrict__ k_buf,
                                                  bf16* __restrict__ v_t,
                                                  bf16* __restrict__ proj_ff) {
  __shared__ bf16 As[2*256*64];
  __shared__ bf16 Bs[2*256*64];
  const int tid = threadIdx.x, w = tid >> 6, l = tid & 63;
  const int l15 = l & 15, h4 = l >> 4;
  const int wr = w >> 2, wc = w & 3;
  const int nwg = gridDim.x, bid = blockIdx.x;
  const int bs = (bid & 7) * (nwg >> 3) + (bid >> 3);   // XCD swizzle (1168 % 8 == 0)
  const int mt = bs & 15, nt = bs >> 4;
  const int m0 = mt * 256, f0 = nt * 256;
  const int wrow = wr * 128, nbase = wc * 64;

  f32x4 acc[8][4];
#pragma unroll
  for (int i = 0; i < 8; i++)
#pragma unroll
    for (int j = 0; j < 4; j++) acc[i][j] = (f32x4){0.f,0.f,0.f,0.f};

  auto fa = [&](int t) -> SrcT { return SrcT{ xn + (size_t)m0 * DIMD + t * 64, (long)DIMD }; };
  auto fb = [&](int t) -> SrcT { return SrcT{ wf + (size_t)f0 * DIMD + t * 64, (long)DIMD }; };
  gemm_core<8>(fa, fb, DIMD / 64, As, Bs, acc, tid, wrow, nbase, l15, h4);

#pragma unroll
  for (int m_ = 0; m_ < 8; m_++)
#pragma unroll
    for (int nf = 0; nf < 4; nf++) {
      int fcol = f0 + nbase + nf*16 + l15;
      if (fcol < FUSEDN) {
#pragma unroll
        for (int j = 0; j < 4; j++) {
          int m = m0 + wrow + m_*16 + h4*4 + j;
          bf16 bv = (bf16)acc[m_][nf][j];
          int b = m >> 11, n = m & 2047;
          if (fcol < 2048) {
            int hh = fcol >> 6, d = fcol & 63;
            q_raw[(((size_t)(b*HEADS + hh) * NN + n) << 6) + d] = bv;
          } else if (fcol < 2112) {
            k_buf[(((size_t)(b*NN + n)) << 6) + (fcol - 2048)] = bv;
          } else if (fcol < 2176) {
            v_t[(((size_t)(b*DH + (fcol - 2112))) << 11) + n] = bv;
          } else {
            proj_ff[((size_t)m << 14) + (fcol - 2176)] = bv;
          }
        }
      }
    }
}

// ---------------- GEMM2: out = [O | ffh](4096x10240) @ Wcat^T -> fp32 ----------------
__global__ __launch_bounds__(512, 2) void k_gemm2(const bf16* __restrict__ u_o,
                                                  const bf16* __restrict__ ffh,
                                                  const bf16* __restrict__ wcat,
                                                  float* __restrict__ out) {
  __shared__ bf16 As[2*128*64];
  __shared__ bf16 Bs[2*256*64];
  const int tid = threadIdx.x, w = tid >> 6, l = tid & 63;
  const int l15 = l & 15, h4 = l >> 4;
  const int wr = w >> 2, wc = w & 3;
  const int bid = blockIdx.x;
  const int bs = (bid & 7) * 32 + (bid >> 3);           // XCD swizzle (256 blocks)
  const int mt = bs & 31, nt = bs >> 5;
  const int m0 = mt * 128, f0 = nt * 256;
  const int wrow = wr * 64, nbase = wc * 64;

  f32x4 acc[4][4];
#pragma unroll
  for (int i = 0; i < 4; i++)
#pragma unroll
    for (int j = 0; j < 4; j++) acc[i][j] = (f32x4){0.f,0.f,0.f,0.f};

  auto fa = [&](int t) -> SrcT {
    int k0 = t * 64;
    if (k0 < DIMD) return SrcT{ u_o + (size_t)m0 * DIMD + k0, (long)DIMD };
    return SrcT{ ffh + (size_t)m0 * 16384 + (k0 - DIMD), (long)16384 };
  };
  auto fb = [&](int t) -> SrcT { return SrcT{ wcat + (size_t)f0 * K2 + t * 64, (long)K2 }; };
  gemm_core<4>(fa, fb, K2 / 64, As, Bs, acc, tid, wrow, nbase, l15, h4);

#pragma unroll
  for (int m_ = 0; m_ < 4; m_++)
#pragma unroll
    for (int nf = 0; nf < 4; nf++) {
      int fcol = f0 + nbase + nf*16 + l15;
#pragma unroll
      for (int j = 0; j < 4; j++) {
        int m = m0 + wrow + m_*16 + h4*4 + j;
        out[(size_t)m * DIMD + fcol] = acc[m_][nf][j];
      }
    }
}

// ---------------- RoPE in-place on q_raw (with 1/8 fold) and k_buf (inverse scale) ----------------
__global__ void k_rope(bf16* __restrict__ q_raw, bf16* __restrict__ k_buf) {
  const long QT = (long)BB*HEADS*NN*32;
  const long TOT = QT + (long)BB*NN*32;
  long gid = (long)blockIdx.x * blockDim.x + threadIdx.x;
  if (gid >= TOT) return;
  bool isq = gid < QT;
  long idx = isq ? gid : gid - QT;
  int  i = (int)(idx & 31);
  long row = idx >> 5;
  int  n = (int)(row & (NN - 1));
  bf16* base = (isq ? q_raw : k_buf) + row * DH;
  float t1 = (float)base[i];
  float t2 = (float)base[i + 32];
  float inv_freq = exp2f((float)i * -0.4152410118f);   // 10000^(-i/32)
  float th = (float)n * inv_freq;
  float sn, cs;
  __sincosf(th, &sn, &cs);
  float power = ((float)n - (float)(NN/2)) * (1.f/512.f);
  float sb = ((float)(2*i) + 25.6f) * (1.f/89.6f);
  float sc = exp2f((isq ? power : -power) * __log2f(sb));
  float mm = isq ? 0.125f : 1.0f;
  float o1 = (t1*cs - t2*sn) * sc * mm;
  float o2 = (t2*cs + t1*sn) * sc * mm;
  base[i]      = (bf16)o1;
  base[i + 32] = (bf16)o2;
}

// ---------------- causal MQA flash attention ----------------
__global__ __launch_bounds__(256) void k_attn(const bf16* __restrict__ qbuf,
                                              const bf16* __restrict__ kbuf,
                                              const bf16* __restrict__ vtb,
                                              bf16* __restrict__ uo) {
  __shared__ bf16 Qs[128*64];
  __shared__ bf16 Ks[32*64];
  __shared__ bf16 Vs[64*32];
  const int tid = threadIdx.x, w = tid >> 6, l = tid & 63;
  const int l15 = l & 15, h4 = l >> 4;
  const int bid = blockIdx.x;
  const int qt = bid & 15, bh = bid >> 4;
  const int h = bh & (HEADS - 1), b = bh >> 5;
  const int q0 = qt * 128;
  const bf16* Qg = qbuf + ((size_t)(b*HEADS + h) * NN + q0) * DH;
  const bf16* Kg = kbuf + (size_t)b * NN * DH;
  const bf16* Vg = vtb + (size_t)b * DH * NN;

#pragma unroll
  for (int c = 0; c < 4; c++) {
    int chunk = c*256 + tid;
    int r = chunk >> 3, cc = chunk & 7;
    int col8 = (cc ^ (r & 7)) << 3;
    gl_lds16(Qg + (size_t)r*DH + col8, Qs + ((size_t)(chunk & ~63) << 3));
  }
  __syncthreads();

  const int wq0 = q0 + w*32;
  bf16x8 qfr[2][2];
#pragma unroll
  for (int qf = 0; qf < 2; qf++)
#pragma unroll
    for (int c = 0; c < 2; c++) {
      int row = w*32 + qf*16 + l15;
      int x = (64*c + 16*h4) ^ (16*(row & 7));
      qfr[qf][c] = *(const bf16x8*)((const char*)Qs + row*128 + x);
    }

  f32x4 zf = {0.f,0.f,0.f,0.f};
  f32x4 o_[2][4];
#pragma unroll
  for (int qf = 0; qf < 2; qf++)
#pragma unroll
    for (int nf = 0; nf < 4; nf++) o_[qf][nf] = zf;
  float mrun[2] = {-3e38f, -3e38f};
  float lrun[2] = {0.f, 0.f};

  const int nsteps = (q0 + 128) >> 5;
  for (int kt = 0; kt < nsteps; kt++) {
    const int kv0 = kt << 5;
    {
      int r = tid >> 3, cc = tid & 7;
      int col8 = (cc ^ (r & 7)) << 3;
      gl_lds16(Kg + (size_t)(kv0 + r)*DH + col8, Ks + ((size_t)(tid & ~63) << 3));
    }
    {
      int d = tid >> 2, cc = tid & 3;
      int col8 = (cc ^ (d & 3)) << 3;
      gl_lds16(Vg + (size_t)d*NN + kv0 + col8, Vs + ((size_t)(tid & ~63) << 3));
    }
    __syncthreads();
    if (kv0 <= wq0 + 31) {
      bf16x8 ka[2][2];
#pragma unroll
      for (int kvf = 0; kvf < 2; kvf++)
#pragma unroll
        for (int c = 0; c < 2; c++) {
          int r = kvf*16 + l15;
          int x = (64*c + 16*h4) ^ (16*(r & 7));
          ka[kvf][c] = *(const bf16x8*)((const char*)Ks + r*128 + x);
        }
      f32x4 st[2][2];
#pragma unroll
      for (int kvf = 0; kvf < 2; kvf++)
#pragma unroll
        for (int qf = 0; qf < 2; qf++) {
          f32x4 s = __builtin_amdgcn_mfma_f32_16x16x32_bf16(ka[kvf][0], qfr[qf][0], zf, 0, 0, 0);
          s = __builtin_amdgcn_mfma_f32_16x16x32_bf16(ka[kvf][1], qfr[qf][1], s, 0, 0, 0);
          st[kvf][qf] = s;
        }
      if (kv0 + 31 > wq0) {
#pragma unroll
        for (int kvf = 0; kvf < 2; kvf++)
#pragma unroll
          for (int j = 0; j < 4; j++) {
            int kvg = kv0 + kvf*16 + h4*4 + j;
#pragma unroll
            for (int qf = 0; qf < 2; qf++) {
              int qg = wq0 + qf*16 + l15;
              if (kvg > qg) st[kvf][qf][j] = -3e38f;
            }
          }
      }
      bf16x8 pa[2];
#pragma unroll
      for (int qf = 0; qf < 2; qf++) {
        float vmax = -3e38f;
#pragma unroll
        for (int kvf = 0; kvf < 2; kvf++)
#pragma unroll
          for (int j = 0; j < 4; j++) vmax = fmaxf(vmax, st[kvf][qf][j]);
        vmax = fmaxf(vmax, __shfl_xor(vmax, 16));
        vmax = fmaxf(vmax, __shfl_xor(vmax, 32));
        float mnew = fmaxf(mrun[qf], vmax);
        float corr = __expf(mrun[qf] - mnew);
        float ps = 0.f;
        float pv_[8];
#pragma unroll
        for (int kvf = 0; kvf < 2; kvf++)
#pragma unroll
          for (int j = 0; j < 4; j++) {
            float p = __expf(st[kvf][qf][j] - mnew);
            pv_[kvf*4 + j] = p; ps += p;
          }
        ps += __shfl_xor(ps, 16);
        ps += __shfl_xor(ps, 32);
        lrun[qf] = lrun[qf]*corr + ps;
        mrun[qf] = mnew;
        bf16x8 t;
#pragma unroll
        for (int i = 0; i < 8; i++) t[i] = (bf16)pv_[i];
        pa[qf] = t;
#pragma unroll
        for (int j = 0; j < 4; j++) {
          float cj = __shfl(corr, (l & 48) | (h4*4 + j), 64);
#pragma unroll
          for (int nf = 0; nf < 4; nf++) o_[qf][nf][j] *= cj;
        }
      }
#pragma unroll
      for (int nf = 0; nf < 4; nf++) {
        int d_ = nf*16 + l15;
        int swz = 16*(d_ & 3);
        const char* vrow = (const char*)Vs + d_*64;
        bf16x4 v0 = *(const bf16x4*)(vrow + ((8*h4) ^ swz));
        bf16x4 v1 = *(const bf16x4*)(vrow + ((8*h4 + 32) ^ swz));
        bf16x8 vb = __builtin_shufflevector(v0, v1, 0,1,2,3,4,5,6,7);
#pragma unroll
        for (int qf = 0; qf < 2; qf++)
          o_[qf][nf] = __builtin_amdgcn_mfma_f32_16x16x32_bf16(pa[qf], vb, o_[qf][nf], 0, 0, 0);
      }
    }
    __syncthreads();
  }
#pragma unroll
  for (int qf = 0; qf < 2; qf++) {
    float inv = 1.f / lrun[qf];
#pragma unroll
    for (int j = 0; j < 4; j++) {
      float ij = __shfl(inv, (l & 48) | (h4*4 + j), 64);
      int qg = wq0 + qf*16 + h4*4 + j;
      size_t rowoff = (size_t)(b*NN + qg) * DIMD + h*DH;
#pragma unroll
      for (int nf = 0; nf < 4; nf++)
        uo[rowoff + nf*16 + l15] = (bf16)(o_[qf][nf][j] * ij);
    }
  }
}

// ---------------- SiLU gating, in-place over ff_x half of proj_ff ----------------
__global__ void k_silu(bf16* __restrict__ pf) {
  const long total4 = (long)MROWS * FFI / 4;
  long stride = (long)gridDim.x * blockDim.x;
  for (long i = (long)blockIdx.x * blockDim.x + threadIdx.x; i < total4; i += stride) {
    long e = i << 2;
    long m = e >> 13;
    int  c = (int)(e & (FFI - 1));
    bf16* px = pf + (m << 14) + c;
    bf16x4 fx = *(const bf16x4*)px;
    bf16x4 gt = *(const bf16x4*)(px + FFI);
    bf16x4 r;
#pragma unroll
    for (int k = 0; k < 4; k++) {
      float g = (float)gt[k], f = (float)fx[k];
      float s = g * (1.f / (1.f + __expf(-g)));
      r[k] = (bf16)(s * f);
    }
    *(bf16x4*)px = r;
  }
}

extern "C" void kernel_launch(void* const* d_in, const int* in_sizes, int n_in,
                              void* d_out, int out_size, void* d_ws, size_t ws_size,
                              hipStream_t stream) {
  const float* x     = (const float*)d_in[0];
  const float* gamma = (const float*)d_in[1];
  const float* Wf    = (const float*)d_in[2];
  const float* Wao   = (const float*)d_in[3];
  const float* Wff   = (const float*)d_in[4];
  float* out = (float*)d_out;
  char* ws = (char*)d_ws;

  size_t o = 0;
  bf16* wfb     = (bf16*)(ws + o); o += (size_t)FUSEDP * DIMD * 2;   // padded
  bf16* wcat    = wfb;                                               // aliased after GEMM1
  bf16* xn      = (bf16*)(ws + o); o += (size_t)MROWS * DIMD * 2;
  bf16* q_raw   = (bf16*)(ws + o); o += (size_t)BB*HEADS*NN*DH * 2;
  bf16* k_buf   = (bf16*)(ws + o); o += (size_t)BB*NN*DH * 2;
  bf16* v_t     = (bf16*)(ws + o); o += (size_t)BB*DH*NN * 2;
  bf16* proj_ff = (bf16*)(ws + o); o += (size_t)MROWS * 2*FFI * 2;
  bf16* u_o     = (bf16*)(ws + o); o += (size_t)MROWS * DIMD * 2;

  k_cvt_flat<<<2048, 256, 0, stream>>>(Wf, wfb, (long)FUSEDN*DIMD/8);
  k_ln<<<MROWS, 256, 0, stream>>>(x, gamma, xn);
  k_gemm1<<<(FUSEDP/256)*(MROWS/256), 512, 0, stream>>>(xn, wfb, q_raw, k_buf, v_t, proj_ff);
  k_cvt_str8<<<512,  256, 0, stream>>>(Wao, wcat, (long)DIMD*DIMD/8, 11, K2, 0);
  k_cvt_str8<<<1024, 256, 0, stream>>>(Wff, wcat, (long)DIMD*FFI/8,  13, K2, DIMD);
  {
    long tot = (long)BB*HEADS*NN*32 + (long)BB*NN*32;
    k_rope<<<(int)((tot + 255) / 256), 256, 0, stream>>>(q_raw, k_buf);
  }
  k_attn<<<BB*HEADS*(NN/128), 256, 0, stream>>>(q_raw, k_buf, v_t, u_o);
  k_silu<<<2048, 256, 0, stream>>>(proj_ff);
  k_gemm2<<<(MROWS/128)*(DIMD/256), 512, 0, stream>>>(u_o, proj_ff, wcat, out);
}

// Round 5
// 820.220 us; speedup vs baseline: 1.1831x; 1.1807x over previous
//
#include <hip/hip_runtime.h>
#include <cstdint>
#include <cstddef>

typedef __bf16 bf16;
typedef float f32x4 __attribute__((ext_vector_type(4)));
typedef bf16  bf16x4 __attribute__((ext_vector_type(4)));
typedef bf16  bf16x8 __attribute__((ext_vector_type(8)));

#define DIMD   2048
#define HEADS  32
#define DH     64
#define FFI    8192
#define FUSEDN 18560
#define FUSEDP 18688   // padded to 146*128
#define BB     2
#define NN     2048
#define MROWS  4096   // BB*NN
#define K2     10240  // DIMD + FFI

// async global->LDS, 16B per lane, wave-uniform LDS base
__device__ __forceinline__ void gl_lds16(const void* g, void* l) {
  __builtin_amdgcn_global_load_lds(
      (__attribute__((address_space(1))) void*)const_cast<void*>(g),
      (__attribute__((address_space(3))) void*)l, 16, 0, 0);
}

// Stage one gl_lds instruction of a [rows][64] bf16 tile into LDS.
// LDS dest linear (gl_lds constraint); T2 swizzle applied on the GLOBAL
// source: LDS chunk (row, c) receives global chunk (row, c^(row&7)).
// THREADS lanes * 16B per instr -> THREADS/8 rows per instr.
template <int THREADS>
__device__ __forceinline__ void stage_i(const bf16* g, long ldk,
                                        bf16* region, int instr, int tid) {
  int row = instr * (THREADS / 8) + (tid >> 3);
  int cs  = (tid & 7) ^ (row & 7);
  gl_lds16(g + (size_t)row * ldk + cs * 8,
           region + (size_t)instr * (THREADS * 8) + (size_t)(tid & ~63) * 8);
}

// ---- m97-style 2-barrier GEMM core: 128x128 tile, BK=64, 256 thr, 32KB LDS.
// Cross-block overlap (3-4 blocks/CU) hides the barrier drains (m97/m114).
template <typename FA, typename FB>
__device__ __forceinline__ void gemm_2ph(FA fa, FB fb, const int NT,
    bf16* As, bf16* Bs, f32x4 (&acc)[4][4],
    const int tid, const int wrow, const int nbase, const int l15, const int h4)
{
  const char* aP[2]; const char* bP[2];
  const int arow = wrow + l15, brow = nbase + l15;
#pragma unroll
  for (int ks = 0; ks < 2; ks++) {
    aP[ks] = (const char*)As + arow * 128 + (((ks * 4 + h4) ^ (arow & 7)) * 16);
    bP[ks] = (const char*)Bs + brow * 128 + (((ks * 4 + h4) ^ (brow & 7)) * 16);
  }
  for (int t = 0; t < NT; ++t) {
    __syncthreads();                       // WAR: all reads of tile t-1 done
    {
      SrcT_fwd:;
      auto a = fa(t); auto b = fb(t);
#pragma unroll
      for (int q = 0; q < 4; q++) stage_i<256>(a.g, a.ldk, As, q, tid);
#pragma unroll
      for (int q = 0; q < 4; q++) stage_i<256>(b.g, b.ldk, Bs, q, tid);
    }
    __syncthreads();                       // full drain (vmcnt0): tile t ready
#pragma unroll
    for (int ks = 0; ks < 2; ks++) {
      bf16x8 af[4], bfr[4];
#pragma unroll
      for (int m_ = 0; m_ < 4; m_++) af[m_]  = *(const bf16x8*)(aP[ks] + m_ * 2048);
#pragma unroll
      for (int n_ = 0; n_ < 4; n_++) bfr[n_] = *(const bf16x8*)(bP[ks] + n_ * 2048);
#pragma unroll
      for (int m_ = 0; m_ < 4; m_++)
#pragma unroll
        for (int n_ = 0; n_ < 4; n_++)
          acc[m_][n_] = __builtin_amdgcn_mfma_f32_16x16x32_bf16(af[m_], bfr[n_], acc[m_][n_], 0, 0, 0);
    }
  }
}

struct SrcT { const bf16* g; long ldk; };

// ---------------- fp32 -> bf16 flat conversion ----------------
__global__ void k_cvt_flat(const float* __restrict__ s, bf16* __restrict__ d, long total8) {
  long stride = (long)gridDim.x * blockDim.x;
  for (long i = (long)blockIdx.x * blockDim.x + threadIdx.x; i < total8; i += stride) {
    long e = i << 3;
    float4 v0 = *(const float4*)(s + e);
    float4 v1 = *(const float4*)(s + e + 4);
    bf16x8 o;
    o[0]=(bf16)v0.x; o[1]=(bf16)v0.y; o[2]=(bf16)v0.z; o[3]=(bf16)v0.w;
    o[4]=(bf16)v1.x; o[5]=(bf16)v1.y; o[6]=(bf16)v1.z; o[7]=(bf16)v1.w;
    *(bf16x8*)(d + e) = o;
  }
}

// ---------------- fp32 -> bf16 strided conversion (pow2 cols) ----------------
__global__ void k_cvt_str8(const float* __restrict__ s, bf16* __restrict__ d,
                           long total8, int colshift, int dstride, int doff) {
  long stride = (long)gridDim.x * blockDim.x;
  for (long i = (long)blockIdx.x * blockDim.x + threadIdx.x; i < total8; i += stride) {
    long e = i << 3;
    long r = e >> colshift;
    int  c = (int)(e & ((1L << colshift) - 1));
    float4 v0 = *(const float4*)(s + e);
    float4 v1 = *(const float4*)(s + e + 4);
    bf16x8 o;
    o[0]=(bf16)v0.x; o[1]=(bf16)v0.y; o[2]=(bf16)v0.z; o[3]=(bf16)v0.w;
    o[4]=(bf16)v1.x; o[5]=(bf16)v1.y; o[6]=(bf16)v1.z; o[7]=(bf16)v1.w;
    *(bf16x8*)(d + r * (long)dstride + doff + c) = o;
  }
}

// ---------------- LayerNorm (per row) -> bf16 ----------------
__global__ __launch_bounds__(256) void k_ln(const float* __restrict__ x,
                                            const float* __restrict__ g,
                                            bf16* __restrict__ xn) {
  int row = blockIdx.x, t = threadIdx.x;
  const float4* xr = (const float4*)(x + (size_t)row * DIMD);
  float4 a = xr[t*2], b = xr[t*2+1];
  float s  = a.x+a.y+a.z+a.w + b.x+b.y+b.z+b.w;
  float s2 = a.x*a.x+a.y*a.y+a.z*a.z+a.w*a.w + b.x*b.x+b.y*b.y+b.z*b.z+b.w*b.w;
  for (int o = 1; o < 64; o <<= 1) { s += __shfl_xor(s, o); s2 += __shfl_xor(s2, o); }
  __shared__ float rs[8];
  if ((t & 63) == 0) { rs[t>>6] = s; rs[4 + (t>>6)] = s2; }
  __syncthreads();
  s = rs[0]+rs[1]+rs[2]+rs[3]; s2 = rs[4]+rs[5]+rs[6]+rs[7];
  float mu = s * (1.f/DIMD);
  float var = s2 * (1.f/DIMD) - mu*mu;
  float rstd = rsqrtf(var + 1e-5f);
  const float4* gr = (const float4*)g;
  float4 g0 = gr[t*2], g1 = gr[t*2+1];
  bf16x8 o;
  o[0]=(bf16)((a.x-mu)*rstd*g0.x); o[1]=(bf16)((a.y-mu)*rstd*g0.y);
  o[2]=(bf16)((a.z-mu)*rstd*g0.z); o[3]=(bf16)((a.w-mu)*rstd*g0.w);
  o[4]=(bf16)((b.x-mu)*rstd*g1.x); o[5]=(bf16)((b.y-mu)*rstd*g1.y);
  o[6]=(bf16)((b.z-mu)*rstd*g1.z); o[7]=(bf16)((b.w-mu)*rstd*g1.w);
  *(bf16x8*)(xn + (size_t)row * DIMD + t*8) = o;
}

// ---------------- GEMM1: proj = xn(4096x2048) @ Wf^T, routed epilogue ----------------
__global__ __launch_bounds__(256, 3) void k_gemm1(const bf16* __restrict__ xn,
                                                  const bf16* __restrict__ wf,
                                                  bf16* __restrict__ q_raw,
                                                  bf16* __restrict__ k_buf,
                                                  bf16* __restrict__ v_t,
                                                  bf16* __restrict__ proj_ff) {
  __shared__ bf16 As[128*64];
  __shared__ bf16 Bs[128*64];
  const int tid = threadIdx.x, w = tid >> 6, l = tid & 63;
  const int l15 = l & 15, h4 = l >> 4;
  const int wrow = (w >> 1) * 64, nbase = (w & 1) * 64;
  const int bid = blockIdx.x;
  const int bs = (bid & 7) * 584 + (bid >> 3);   // XCD swizzle (4672 = 8*584)
  const int mt = bs / 146, nt = bs - mt * 146;   // nt fastest: same-XCD shares A panel
  const int m0 = mt * 128, f0 = nt * 128;

  f32x4 acc[4][4];
#pragma unroll
  for (int i = 0; i < 4; i++)
#pragma unroll
    for (int j = 0; j < 4; j++) acc[i][j] = (f32x4){0.f,0.f,0.f,0.f};

  auto fa = [&](int t) -> SrcT { return SrcT{ xn + (size_t)m0 * DIMD + t * 64, (long)DIMD }; };
  auto fb = [&](int t) -> SrcT { return SrcT{ wf + (size_t)f0 * DIMD + t * 64, (long)DIMD }; };
  gemm_2ph(fa, fb, DIMD / 64, As, Bs, acc, tid, wrow, nbase, l15, h4);

#pragma unroll
  for (int m_ = 0; m_ < 4; m_++)
#pragma unroll
    for (int nf = 0; nf < 4; nf++) {
      int fcol = f0 + nbase + nf*16 + l15;
      if (fcol < FUSEDN) {
#pragma unroll
        for (int j = 0; j < 4; j++) {
          int m = m0 + wrow + m_*16 + h4*4 + j;
          bf16 bv = (bf16)acc[m_][nf][j];
          int b = m >> 11, n = m & 2047;
          if (fcol < 2048) {
            int hh = fcol >> 6, d = fcol & 63;
            q_raw[(((size_t)(b*HEADS + hh) * NN + n) << 6) + d] = bv;
          } else if (fcol < 2112) {
            k_buf[(((size_t)(b*NN + n)) << 6) + (fcol - 2048)] = bv;
          } else if (fcol < 2176) {
            v_t[(((size_t)(b*DH + (fcol - 2112))) << 11) + n] = bv;
          } else {
            proj_ff[((size_t)m << 14) + (fcol - 2176)] = bv;
          }
        }
      }
    }
}

// ---------------- GEMM2: out = [O | ffh](4096x10240) @ Wcat^T -> fp32 ----------------
__global__ __launch_bounds__(256, 3) void k_gemm2(const bf16* __restrict__ u_o,
                                                  const bf16* __restrict__ ffh,
                                                  const bf16* __restrict__ wcat,
                                                  float* __restrict__ out) {
  __shared__ bf16 As[128*64];
  __shared__ bf16 Bs[128*64];
  const int tid = threadIdx.x, w = tid >> 6, l = tid & 63;
  const int l15 = l & 15, h4 = l >> 4;
  const int wrow = (w >> 1) * 64, nbase = (w & 1) * 64;
  const int bid = blockIdx.x;
  const int bs = (bid & 7) * 64 + (bid >> 3);    // XCD swizzle (512 = 8*64)
  const int mt = bs >> 4, nt = bs & 15;
  const int m0 = mt * 128, f0 = nt * 128;

  f32x4 acc[4][4];
#pragma unroll
  for (int i = 0; i < 4; i++)
#pragma unroll
    for (int j = 0; j < 4; j++) acc[i][j] = (f32x4){0.f,0.f,0.f,0.f};

  auto fa = [&](int t) -> SrcT {
    if (t < 32) return SrcT{ u_o + (size_t)m0 * DIMD + t * 64, (long)DIMD };
    return SrcT{ ffh + (size_t)m0 * 16384 + (t - 32) * 64, (long)16384 };
  };
  auto fb = [&](int t) -> SrcT { return SrcT{ wcat + (size_t)f0 * K2 + t * 64, (long)K2 }; };
  gemm_2ph(fa, fb, K2 / 64, As, Bs, acc, tid, wrow, nbase, l15, h4);

#pragma unroll
  for (int m_ = 0; m_ < 4; m_++)
#pragma unroll
    for (int nf = 0; nf < 4; nf++) {
      int fcol = f0 + nbase + nf*16 + l15;
#pragma unroll
      for (int j = 0; j < 4; j++) {
        int m = m0 + wrow + m_*16 + h4*4 + j;
        out[(size_t)m * DIMD + fcol] = acc[m_][nf][j];
      }
    }
}

// ---------------- RoPE in-place on q_raw (with 1/8 fold) and k_buf (inverse scale) ----------------
__global__ void k_rope(bf16* __restrict__ q_raw, bf16* __restrict__ k_buf) {
  const long QT = (long)BB*HEADS*NN*32;
  const long TOT = QT + (long)BB*NN*32;
  long gid = (long)blockIdx.x * blockDim.x + threadIdx.x;
  if (gid >= TOT) return;
  bool isq = gid < QT;
  long idx = isq ? gid : gid - QT;
  int  i = (int)(idx & 31);
  long row = idx >> 5;
  int  n = (int)(row & (NN - 1));
  bf16* base = (isq ? q_raw : k_buf) + row * DH;
  float t1 = (float)base[i];
  float t2 = (float)base[i + 32];
  float inv_freq = exp2f((float)i * -0.4152410118f);   // 10000^(-i/32)
  float th = (float)n * inv_freq;
  float sn, cs;
  __sincosf(th, &sn, &cs);
  float power = ((float)n - (float)(NN/2)) * (1.f/512.f);
  float sb = ((float)(2*i) + 25.6f) * (1.f/89.6f);
  float sc = exp2f((isq ? power : -power) * __log2f(sb));
  float mm = isq ? 0.125f : 1.0f;
  float o1 = (t1*cs - t2*sn) * sc * mm;
  float o2 = (t2*cs + t1*sn) * sc * mm;
  base[i]      = (bf16)o1;
  base[i + 32] = (bf16)o2;
}

// ---------------- causal MQA flash attention ----------------
__global__ __launch_bounds__(256) void k_attn(const bf16* __restrict__ qbuf,
                                              const bf16* __restrict__ kbuf,
                                              const bf16* __restrict__ vtb,
                                              bf16* __restrict__ uo) {
  __shared__ bf16 Qs[128*64];
  __shared__ bf16 Ks[32*64];
  __shared__ bf16 Vs[64*32];
  const int tid = threadIdx.x, w = tid >> 6, l = tid & 63;
  const int l15 = l & 15, h4 = l >> 4;
  const int bid = blockIdx.x;
  const int qt = bid & 15, bh = bid >> 4;
  const int h = bh & (HEADS - 1), b = bh >> 5;
  const int q0 = qt * 128;
  const bf16* Qg = qbuf + ((size_t)(b*HEADS + h) * NN + q0) * DH;
  const bf16* Kg = kbuf + (size_t)b * NN * DH;
  const bf16* Vg = vtb + (size_t)b * DH * NN;

#pragma unroll
  for (int c = 0; c < 4; c++) {
    int chunk = c*256 + tid;
    int r = chunk >> 3, cc = chunk & 7;
    int col8 = (cc ^ (r & 7)) << 3;
    gl_lds16(Qg + (size_t)r*DH + col8, Qs + ((size_t)(chunk & ~63) << 3));
  }
  __syncthreads();

  const int wq0 = q0 + w*32;
  bf16x8 qfr[2][2];
#pragma unroll
  for (int qf = 0; qf < 2; qf++)
#pragma unroll
    for (int c = 0; c < 2; c++) {
      int row = w*32 + qf*16 + l15;
      int x = (64*c + 16*h4) ^ (16*(row & 7));
      qfr[qf][c] = *(const bf16x8*)((const char*)Qs + row*128 + x);
    }

  f32x4 zf = {0.f,0.f,0.f,0.f};
  f32x4 o_[2][4];
#pragma unroll
  for (int qf = 0; qf < 2; qf++)
#pragma unroll
    for (int nf = 0; nf < 4; nf++) o_[qf][nf] = zf;
  float mrun[2] = {-3e38f, -3e38f};
  float lrun[2] = {0.f, 0.f};

  const int nsteps = (q0 + 128) >> 5;
  for (int kt = 0; kt < nsteps; kt++) {
    const int kv0 = kt << 5;
    {
      int r = tid >> 3, cc = tid & 7;
      int col8 = (cc ^ (r & 7)) << 3;
      gl_lds16(Kg + (size_t)(kv0 + r)*DH + col8, Ks + ((size_t)(tid & ~63) << 3));
    }
    {
      int d = tid >> 2, cc = tid & 3;
      int col8 = (cc ^ (d & 3)) << 3;
      gl_lds16(Vg + (size_t)d*NN + kv0 + col8, Vs + ((size_t)(tid & ~63) << 3));
    }
    __syncthreads();
    if (kv0 <= wq0 + 31) {
      bf16x8 ka[2][2];
#pragma unroll
      for (int kvf = 0; kvf < 2; kvf++)
#pragma unroll
        for (int c = 0; c < 2; c++) {
          int r = kvf*16 + l15;
          int x = (64*c + 16*h4) ^ (16*(r & 7));
          ka[kvf][c] = *(const bf16x8*)((const char*)Ks + r*128 + x);
        }
      f32x4 st[2][2];
#pragma unroll
      for (int kvf = 0; kvf < 2; kvf++)
#pragma unroll
        for (int qf = 0; qf < 2; qf++) {
          f32x4 s = __builtin_amdgcn_mfma_f32_16x16x32_bf16(ka[kvf][0], qfr[qf][0], zf, 0, 0, 0);
          s = __builtin_amdgcn_mfma_f32_16x16x32_bf16(ka[kvf][1], qfr[qf][1], s, 0, 0, 0);
          st[kvf][qf] = s;
        }
      if (kv0 + 31 > wq0) {
#pragma unroll
        for (int kvf = 0; kvf < 2; kvf++)
#pragma unroll
          for (int j = 0; j < 4; j++) {
            int kvg = kv0 + kvf*16 + h4*4 + j;
#pragma unroll
            for (int qf = 0; qf < 2; qf++) {
              int qg = wq0 + qf*16 + l15;
              if (kvg > qg) st[kvf][qf][j] = -3e38f;
            }
          }
      }
      bf16x8 pa[2];
#pragma unroll
      for (int qf = 0; qf < 2; qf++) {
        float vmax = -3e38f;
#pragma unroll
        for (int kvf = 0; kvf < 2; kvf++)
#pragma unroll
          for (int j = 0; j < 4; j++) vmax = fmaxf(vmax, st[kvf][qf][j]);
        vmax = fmaxf(vmax, __shfl_xor(vmax, 16));
        vmax = fmaxf(vmax, __shfl_xor(vmax, 32));
        float mnew = fmaxf(mrun[qf], vmax);
        float corr = __expf(mrun[qf] - mnew);
        float ps = 0.f;
        float pv_[8];
#pragma unroll
        for (int kvf = 0; kvf < 2; kvf++)
#pragma unroll
          for (int j = 0; j < 4; j++) {
            float p = __expf(st[kvf][qf][j] - mnew);
            pv_[kvf*4 + j] = p; ps += p;
          }
        ps += __shfl_xor(ps, 16);
        ps += __shfl_xor(ps, 32);
        lrun[qf] = lrun[qf]*corr + ps;
        mrun[qf] = mnew;
        bf16x8 t;
#pragma unroll
        for (int i = 0; i < 8; i++) t[i] = (bf16)pv_[i];
        pa[qf] = t;
#pragma unroll
        for (int j = 0; j < 4; j++) {
          float cj = __shfl(corr, (l & 48) | (h4*4 + j), 64);
#pragma unroll
          for (int nf = 0; nf < 4; nf++) o_[qf][nf][j] *= cj;
        }
      }
#pragma unroll
      for (int nf = 0; nf < 4; nf++) {
        int d_ = nf*16 + l15;
        int swz = 16*(d_ & 3);
        const char* vrow = (const char*)Vs + d_*64;
        bf16x4 v0 = *(const bf16x4*)(vrow + ((8*h4) ^ swz));
        bf16x4 v1 = *(const bf16x4*)(vrow + ((8*h4 + 32) ^ swz));
        bf16x8 vb = __builtin_shufflevector(v0, v1, 0,1,2,3,4,5,6,7);
#pragma unroll
        for (int qf = 0; qf < 2; qf++)
          o_[qf][nf] = __builtin_amdgcn_mfma_f32_16x16x32_bf16(pa[qf], vb, o_[qf][nf], 0, 0, 0);
      }
    }
    __syncthreads();
  }
#pragma unroll
  for (int qf = 0; qf < 2; qf++) {
    float inv = 1.f / lrun[qf];
#pragma unroll
    for (int j = 0; j < 4; j++) {
      float ij = __shfl(inv, (l & 48) | (h4*4 + j), 64);
      int qg = wq0 + qf*16 + h4*4 + j;
      size_t rowoff = (size_t)(b*NN + qg) * DIMD + h*DH;
#pragma unroll
      for (int nf = 0; nf < 4; nf++)
        uo[rowoff + nf*16 + l15] = (bf16)(o_[qf][nf][j] * ij);
    }
  }
}

// ---------------- SiLU gating, in-place over ff_x half of proj_ff ----------------
__global__ void k_silu(bf16* __restrict__ pf) {
  const long total4 = (long)MROWS * FFI / 4;
  long stride = (long)gridDim.x * blockDim.x;
  for (long i = (long)blockIdx.x * blockDim.x + threadIdx.x; i < total4; i += stride) {
    long e = i << 2;
    long m = e >> 13;
    int  c = (int)(e & (FFI - 1));
    bf16* px = pf + (m << 14) + c;
    bf16x4 fx = *(const bf16x4*)px;
    bf16x4 gt = *(const bf16x4*)(px + FFI);
    bf16x4 r;
#pragma unroll
    for (int k = 0; k < 4; k++) {
      float g = (float)gt[k], f = (float)fx[k];
      float s = g * (1.f / (1.f + __expf(-g)));
      r[k] = (bf16)(s * f);
    }
    *(bf16x4*)px = r;
  }
}

extern "C" void kernel_launch(void* const* d_in, const int* in_sizes, int n_in,
                              void* d_out, int out_size, void* d_ws, size_t ws_size,
                              hipStream_t stream) {
  const float* x     = (const float*)d_in[0];
  const float* gamma = (const float*)d_in[1];
  const float* Wf    = (const float*)d_in[2];
  const float* Wao   = (const float*)d_in[3];
  const float* Wff   = (const float*)d_in[4];
  float* out = (float*)d_out;
  char* ws = (char*)d_ws;

  size_t o = 0;
  bf16* wfb     = (bf16*)(ws + o); o += (size_t)FUSEDP * DIMD * 2;   // padded
  bf16* wcat    = wfb;                                               // aliased after GEMM1
  bf16* xn      = (bf16*)(ws + o); o += (size_t)MROWS * DIMD * 2;
  bf16* q_raw   = (bf16*)(ws + o); o += (size_t)BB*HEADS*NN*DH * 2;
  bf16* k_buf   = (bf16*)(ws + o); o += (size_t)BB*NN*DH * 2;
  bf16* v_t     = (bf16*)(ws + o); o += (size_t)BB*DH*NN * 2;
  bf16* proj_ff = (bf16*)(ws + o); o += (size_t)MROWS * 2*FFI * 2;
  bf16* u_o     = (bf16*)(ws + o); o += (size_t)MROWS * DIMD * 2;

  k_cvt_flat<<<2048, 256, 0, stream>>>(Wf, wfb, (long)FUSEDN*DIMD/8);
  k_ln<<<MROWS, 256, 0, stream>>>(x, gamma, xn);
  k_gemm1<<<(FUSEDP/128)*(MROWS/128), 256, 0, stream>>>(xn, wfb, q_raw, k_buf, v_t, proj_ff);
  k_cvt_str8<<<512,  256, 0, stream>>>(Wao, wcat, (long)DIMD*DIMD/8, 11, K2, 0);
  k_cvt_str8<<<1024, 256, 0, stream>>>(Wff, wcat, (long)DIMD*FFI/8,  13, K2, DIMD);
  {
    long tot = (long)BB*HEADS*NN*32 + (long)BB*NN*32;
    k_rope<<<(int)((tot + 255) / 256), 256, 0, stream>>>(q_raw, k_buf);
  }
  k_attn<<<BB*HEADS*(NN/128), 256, 0, stream>>>(q_raw, k_buf, v_t, u_o);
  k_silu<<<2048, 256, 0, stream>>>(proj_ff);
  k_gemm2<<<(MROWS/128)*(DIMD/128), 256, 0, stream>>>(u_o, proj_ff, wcat, out);
}